// Round 6
// baseline (1021.588 us; speedup 1.0000x reference)
//
#include <hip/hip_runtime.h>
#include <cstdint>

// ---------------------------------------------------------------------------
// MXFP4 GPT-OSS MoE experts: dense all-expert GLU MLP.
// Round 10: both GEMMs keep the proven 3-slot ring / distance-2 / counted
// vmcnt / single-barrier schedule, but wave tile grows 64x64 -> 128x64
// (4 waves/block, 256 thr, 2Mx2N; 32 MFMA per wave per K-step; acc[8][4]).
// FLOP per LDS byte +33%, MFMA per barrier x2 -> predicted MfmaUtil ~55%.
// 6 loads/thread -> vmcnt(6). gemm2 K-split 12. dq/cvt/bias unchanged.
// ---------------------------------------------------------------------------

typedef float  floatx4 __attribute__((ext_vector_type(4)));
typedef __bf16 bf16x8  __attribute__((ext_vector_type(8)));

#define E8   8
#define Hdim 2880
#define Idim 2880
#define Ttok 1024
#define R1   5760   // 2*I rows of gate_up weights
#define Gg   90     // scale groups per row (K/32)
#define K2   (E8 * Idim)   // 23040 flattened (e,i) K for GEMM2

__device__ __forceinline__ void load_lds16(const void* gptr, void* lptr) {
  __builtin_amdgcn_global_load_lds(
      (const __attribute__((address_space(1))) uint32_t*)gptr,
      (__attribute__((address_space(3))) uint32_t*)lptr, 16, 0, 0);
}

__device__ __forceinline__ uint32_t f2bf(float f) {  // RTN-even fp32->bf16
  uint32_t u = __float_as_uint(f);
  return (u + 0x7FFFu + ((u >> 16) & 1u)) >> 16;
}

__device__ __forceinline__ uint32_t perm(uint32_t hi, uint32_t lo, uint32_t sel) {
  return __builtin_amdgcn_perm(hi, lo, sel);
}

// Per-scale-group LUT: bf16 bit patterns of FP4 magnitudes 0..7 scaled by
// 2^(s-127), split into low/high bytes for v_perm lookup. Entry 0 stays 0.
struct DqLut { uint32_t Ll, Lh, Hl, Hh; };

__device__ __forceinline__ DqLut make_lut(int s) {
  uint32_t A  = ((uint32_t)(s - 127) << 7) & 0xFFFFu;
  uint32_t e1 = (0x3F00u + A) & 0xFFFFu, e2 = (0x3F80u + A) & 0xFFFFu;
  uint32_t e3 = (0x3FC0u + A) & 0xFFFFu, e4 = (0x4000u + A) & 0xFFFFu;
  uint32_t e5 = (0x4040u + A) & 0xFFFFu, e6 = (0x4080u + A) & 0xFFFFu;
  uint32_t e7 = (0x40C0u + A) & 0xFFFFu;
  uint32_t B01 = e1 << 16, B23 = e2 | (e3 << 16);
  uint32_t B45 = e4 | (e5 << 16), B67 = e6 | (e7 << 16);
  DqLut L;
  L.Ll = perm(B23, B01, 0x06040200u);
  L.Hl = perm(B23, B01, 0x07050301u);
  L.Lh = perm(B67, B45, 0x06040200u);
  L.Hh = perm(B67, B45, 0x07050301u);
  return L;
}

// 4 source dwords (1 packed byte each) -> 8 bf16 (4 dwords), interleaved order.
__device__ __forceinline__ uint4 dq8(const DqLut& L, int4 wr) {
  uint32_t p = perm((uint32_t)wr.y, (uint32_t)wr.x, 0x04000400u);
  uint32_t q = perm((uint32_t)wr.w, (uint32_t)wr.z, 0x04000400u);
  uint32_t w = perm(q, p, 0x05040100u);
  uint32_t ilo = w & 0x07070707u;
  uint32_t ihi = (w >> 4) & 0x07070707u;
  uint32_t Llo = perm(L.Lh, L.Ll, ilo);
  uint32_t Hlo = perm(L.Hh, L.Hl, ilo) | ((w << 4) & 0x80808080u);
  uint32_t Lhi = perm(L.Lh, L.Ll, ihi);
  uint32_t Hhi = perm(L.Hh, L.Hl, ihi) | (w & 0x80808080u);
  uint32_t t0 = perm(Hlo, Llo, 0x05010400u);
  uint32_t t1 = perm(Hlo, Llo, 0x07030602u);
  uint32_t t2 = perm(Hhi, Lhi, 0x05010400u);
  uint32_t t3 = perm(Hhi, Lhi, 0x07030602u);
  uint4 o;
  o.x = perm(t2, t0, 0x05040100u);
  o.y = perm(t2, t0, 0x07060302u);
  o.z = perm(t3, t1, 0x05040100u);
  o.w = perm(t3, t1, 0x07060302u);
  return o;
}

// ---------------------------------------------------------------------------
__global__ void cvt_x_kernel(const float* __restrict__ x, uint16_t* __restrict__ xb, int n) {
  int i = (blockIdx.x * 256 + threadIdx.x) * 4;
  if (i >= n) return;
  float4 v = *(const float4*)(x + i);
  ushort4 o = make_ushort4((uint16_t)f2bf(v.x), (uint16_t)f2bf(v.y),
                           (uint16_t)f2bf(v.z), (uint16_t)f2bf(v.w));
  *(ushort4*)(xb + i) = o;
}

// W1 pre-dequant, coalesced: one 16B granule (4 packed words -> 8 bf16) per
// thread; 4 threads share a scale group. 16B/lane contiguous read AND write.
__global__ void dq_w_kernel(const int* __restrict__ blocks, const int* __restrict__ scales,
                            uint16_t* __restrict__ wd) {
  size_t q = (size_t)blockIdx.x * 256 + threadIdx.x;
  size_t g = q >> 2;
  int part = (int)(q & 3);
  int4 w = ((const int4*)(blocks + g * 16))[part];
  DqLut L = make_lut(scales[g]);
  *(uint4*)(wd + g * 32 + part * 8) = dq8(L, w);
}

// W2 pre-dequant TRANSPOSED + coalesced: [e][h][i] blocks -> [h][e*Idim+i].
__global__ void dq_w2t_kernel(const int* __restrict__ blocks, const int* __restrict__ scales,
                              uint16_t* __restrict__ wt) {
  size_t q = (size_t)blockIdx.x * 256 + threadIdx.x;
  size_t g = q >> 2;
  int part = (int)(q & 3);
  int e  = (int)(g / ((size_t)Hdim * Gg));
  int rm = (int)(g % ((size_t)Hdim * Gg));
  int h  = rm / Gg;
  int ig = rm % Gg;
  int4 w = ((const int4*)(blocks + g * 16))[part];
  DqLut L = make_lut(scales[g]);
  *(uint4*)(wt + ((size_t)h * E8 + e) * Idim + (size_t)ig * 32 + part * 8) = dq8(L, w);
}

// out[t,h] = sum_e rw[t,e] * down_bias[e,h]   (gemm2 atomicAdds on top)
__global__ void bias_init_kernel(const float* __restrict__ rw, const float* __restrict__ bias,
                                 float* __restrict__ out) {
  int t  = blockIdx.y;
  int h4 = (blockIdx.x * 256 + threadIdx.x) * 4;
  if (h4 >= Hdim) return;
  float4 s = make_float4(0.f, 0.f, 0.f, 0.f);
  #pragma unroll
  for (int e = 0; e < E8; ++e) {
    float w = rw[t * E8 + e];
    float4 b = *(const float4*)(bias + (size_t)e * Hdim + h4);
    s.x += w * b.x; s.y += w * b.y; s.z += w * b.z; s.w += w * b.w;
  }
  *(float4*)(out + (size_t)t * Hdim + h4) = s;
}

// ---------------------------------------------------------------------------
// GEMM1: BM=256 x BN=128 f-rows x BK=32. 256 thr = 4 waves (2Mx2N), wave
// tile 128x64 (acc[8][4], 32 MFMA per K-step). 3-slot 72KB LDS ring,
// distance-2 prefetch, vmcnt(6) + single s_barrier per K-step, setprio
// around MFMA cluster. 6 load_lds16 per thread per K-step (4 A + 2 B).
// Swizzle: granule p holds global granule p ^ ((row>>1)&3) (rows 64B).
// Epilogue: GLU + bias, pre-multiply rw[t,e], store bf16 act[t][(e,i)].
__global__ __launch_bounds__(256, 2) void gemm1_dp_kernel(
    const uint16_t* __restrict__ xb, const uint16_t* __restrict__ w1d,
    const float* __restrict__ bias, const float* __restrict__ rw,
    uint16_t* __restrict__ act) {
  extern __shared__ uint16_t smem[];          // 3*8192 (A) + 3*4096 (B)
  uint16_t* sAr = smem;                       // [3][256*32]
  uint16_t* sBr = smem + 3 * 8192;            // [3][128*32]
  const int tid  = threadIdx.x;
  const int lane = tid & 63, wv = tid >> 6;   // 4 waves
  const int wm = wv >> 1, wn = wv & 1;        // 2M x 2N, wave tile 128x64
  const int col = lane & 15, quad = lane >> 4;
  const int e  = blockIdx.z;
  const int t0 = blockIdx.x * 256;
  const int i0 = blockIdx.y * 64;

  floatx4 acc[8][4] = {};

  // A: 256 rows x 4 granules = 1024 -> 4 issues of 256. B: 128x4 = 2 issues.
  const uint16_t* aSrc[4];
  const uint16_t* bSrc[2];
  int aOff[4], bOff[2];
  #pragma unroll
  for (int q = 0; q < 4; ++q) {
    int L = q * 256 + tid;
    int r = L >> 2;
    int g = (L & 3) ^ ((r >> 1) & 3);
    aSrc[q] = xb + (size_t)(t0 + r) * Hdim + g * 8;
    aOff[q] = (q * 256 + wv * 64) * 8;
  }
  #pragma unroll
  for (int q = 0; q < 2; ++q) {
    int L = q * 256 + tid;
    int rb = L >> 2;
    int gb = (L & 3) ^ ((rb >> 1) & 3);
    int orig = 2 * (((rb >> 6) << 5) + (rb & 31)) + ((rb >> 5) & 1);  // deinterleave
    bSrc[q] = w1d + ((size_t)e * R1 + 2 * i0 + orig) * Hdim + gb * 8;
    bOff[q] = (q * 256 + wv * 64) * 8;
  }

  auto STAGE = [&](int kt, int slot) {
    const int k0 = kt * 32;
    uint16_t* A = sAr + slot * 8192;
    uint16_t* B = sBr + slot * 4096;
    #pragma unroll
    for (int q = 0; q < 4; ++q) load_lds16(aSrc[q] + k0, A + aOff[q]);
    #pragma unroll
    for (int q = 0; q < 2; ++q) load_lds16(bSrc[q] + k0, B + bOff[q]);
  };

  STAGE(0, 0);
  STAGE(1, 1);

  int sr = 0;  // read slot = j % 3
  for (int j = 0; j < 90; ++j) {
    // Drain ONLY tile j (own 6 loads); tiles j+1, j+2 stay in flight.
    asm volatile("s_waitcnt vmcnt(6)" ::: "memory");
    __builtin_amdgcn_s_barrier();          // all waves' tile-j DMA landed
    asm volatile("" ::: "memory");         // pin reads below the barrier
    int js = j + 2; if (js > 89) js = 89;  // clamped tail restage (harmless)
    int sw = sr + 2; if (sw >= 3) sw -= 3; // slot of tile j-1: freed last iter
    STAGE(js, sw);

    const uint16_t* A = sAr + sr * 8192;
    const uint16_t* B = sBr + sr * 4096;
    bf16x8 af[8], bfr[4];
    #pragma unroll
    for (int fm = 0; fm < 8; ++fm) {
      int row = wm * 128 + fm * 16 + col;
      int g = quad ^ ((row >> 1) & 3);
      af[fm] = *(const bf16x8*)&A[row * 32 + g * 8];
    }
    #pragma unroll
    for (int fn = 0; fn < 4; ++fn) {
      int row = wn * 64 + fn * 16 + col;
      int g = quad ^ ((row >> 1) & 3);
      bfr[fn] = *(const bf16x8*)&B[row * 32 + g * 8];
    }
    __builtin_amdgcn_s_setprio(1);
    #pragma unroll
    for (int fm = 0; fm < 8; ++fm)
      #pragma unroll
      for (int fn = 0; fn < 4; ++fn)
        acc[fm][fn] = __builtin_amdgcn_mfma_f32_16x16x32_bf16(
            af[fm], bfr[fn], acc[fm][fn], 0, 0, 0);
    __builtin_amdgcn_s_setprio(0);
    sr = (sr + 1 == 3) ? 0 : sr + 1;
  }

  #pragma unroll
  for (int fm = 0; fm < 8; ++fm) {
    #pragma unroll
    for (int p = 0; p < 2; ++p) {
      floatx4 ga = acc[fm][p], ua = acc[fm][p + 2];
      int ig = i0 + wn * 32 + p * 16 + col;
      float bg = bias[(size_t)e * R1 + 2 * ig];
      float bu = bias[(size_t)e * R1 + 2 * ig + 1];
      #pragma unroll
      for (int r = 0; r < 4; ++r) {
        int t = t0 + wm * 128 + fm * 16 + quad * 4 + r;
        float gate = fminf(ga[r] + bg, 7.0f);
        float up   = fminf(fmaxf(ua[r] + bu, -7.0f), 7.0f);
        float glu  = gate / (1.0f + __expf(-1.702f * gate));
        float a    = rw[t * E8 + e] * (up + 1.0f) * glu;
        act[((size_t)t * E8 + e) * Idim + ig] = (uint16_t)f2bf(a);
      }
    }
  }
}

// ---------------------------------------------------------------------------
// GEMM2: M=1024 x N=2880(pad 23rd block) x K=23040. BM=256, BN=128, BK=32,
// K-split 12 -> grid (4,23,12)=1104 blocks, 60 iters each. 256 thr = 4 waves
// (2Mx2N), wave tile 128x64. Same 3-slot ring / vmcnt(6) / single barrier.
// B staging rows clamped to h<=2879; epilogue atomicAdd guarded h<2880.
__global__ __launch_bounds__(256, 2) void gemm2_dp_kernel(
    const uint16_t* __restrict__ actT, const uint16_t* __restrict__ w2t,
    float* __restrict__ out) {
  extern __shared__ uint16_t smem[];          // 3*8192 (A) + 3*4096 (B)
  uint16_t* sAr = smem;                       // [3][256*32]
  uint16_t* sBr = smem + 3 * 8192;            // [3][128*32]
  const int tid  = threadIdx.x;
  const int lane = tid & 63, wv = tid >> 6;
  const int wm = wv >> 1, wn = wv & 1;        // 2M x 2N, wave tile 128x64
  const int col = lane & 15, quad = lane >> 4;
  const int t0 = blockIdx.x * 256;
  const int h0 = blockIdx.y * 128;            // last block: 2816..2943 (pad)
  const int kbase = blockIdx.z * (K2 / 12);   // 1920 per split

  floatx4 acc[8][4] = {};

  const uint16_t* aSrc[4];
  const uint16_t* bSrc[2];
  int aOff[4], bOff[2];
  #pragma unroll
  for (int q = 0; q < 4; ++q) {
    int L = q * 256 + tid;
    int r = L >> 2;
    int g = (L & 3) ^ ((r >> 1) & 3);
    aSrc[q] = actT + (size_t)(t0 + r) * K2 + kbase + g * 8;
    aOff[q] = (q * 256 + wv * 64) * 8;
  }
  #pragma unroll
  for (int q = 0; q < 2; ++q) {
    int L = q * 256 + tid;
    int rb = L >> 2;
    int gb = (L & 3) ^ ((rb >> 1) & 3);
    int hb = h0 + rb; if (hb > Hdim - 1) hb = Hdim - 1;   // pad-tile clamp
    bSrc[q] = w2t + (size_t)hb * K2 + kbase + gb * 8;
    bOff[q] = (q * 256 + wv * 64) * 8;
  }

  auto STAGE = [&](int kt, int slot) {
    const int k0 = kt * 32;
    uint16_t* A = sAr + slot * 8192;
    uint16_t* B = sBr + slot * 4096;
    #pragma unroll
    for (int q = 0; q < 4; ++q) load_lds16(aSrc[q] + k0, A + aOff[q]);
    #pragma unroll
    for (int q = 0; q < 2; ++q) load_lds16(bSrc[q] + k0, B + bOff[q]);
  };

  STAGE(0, 0);
  STAGE(1, 1);

  int sr = 0;  // read slot = j % 3
  for (int j = 0; j < 60; ++j) {
    asm volatile("s_waitcnt vmcnt(6)" ::: "memory");
    __builtin_amdgcn_s_barrier();
    asm volatile("" ::: "memory");
    int js = j + 2; if (js > 59) js = 59;
    int sw = sr + 2; if (sw >= 3) sw -= 3;
    STAGE(js, sw);

    const uint16_t* A = sAr + sr * 8192;
    const uint16_t* B = sBr + sr * 4096;
    bf16x8 af[8], bfr[4];
    #pragma unroll
    for (int fm = 0; fm < 8; ++fm) {
      int row = wm * 128 + fm * 16 + col;
      int g = quad ^ ((row >> 1) & 3);
      af[fm] = *(const bf16x8*)&A[row * 32 + g * 8];
    }
    #pragma unroll
    for (int fn = 0; fn < 4; ++fn) {
      int row = wn * 64 + fn * 16 + col;
      int g = quad ^ ((row >> 1) & 3);
      bfr[fn] = *(const bf16x8*)&B[row * 32 + g * 8];
    }
    __builtin_amdgcn_s_setprio(1);
    #pragma unroll
    for (int fm = 0; fm < 8; ++fm)
      #pragma unroll
      for (int fn = 0; fn < 4; ++fn)
        acc[fm][fn] = __builtin_amdgcn_mfma_f32_16x16x32_bf16(
            af[fm], bfr[fn], acc[fm][fn], 0, 0, 0);
    __builtin_amdgcn_s_setprio(0);
    sr = (sr + 1 == 3) ? 0 : sr + 1;
  }

  #pragma unroll
  for (int fm = 0; fm < 8; ++fm)
    #pragma unroll
    for (int fn = 0; fn < 4; ++fn) {
      int h = h0 + wn * 64 + fn * 16 + col;
      if (h < Hdim) {
        #pragma unroll
        for (int r = 0; r < 4; ++r) {
          int t = t0 + wm * 128 + fm * 16 + quad * 4 + r;
          atomicAdd(out + (size_t)t * Hdim + h, acc[fm][fn][r]);
        }
      }
    }
}

// ---------------------------------------------------------------------------
extern "C" void kernel_launch(void* const* d_in, const int* in_sizes, int n_in,
                              void* d_out, int out_size, void* d_ws, size_t ws_size,
                              hipStream_t stream) {
  (void)in_sizes; (void)n_in; (void)out_size; (void)ws_size;
  const float* x        = (const float*)d_in[0];
  const float* rw       = (const float*)d_in[1];
  const int*   gub_b    = (const int*)d_in[2];
  const int*   gub_s    = (const int*)d_in[3];
  const float* gub_bias = (const float*)d_in[4];
  const int*   dwn_b    = (const int*)d_in[5];
  const int*   dwn_s    = (const int*)d_in[6];
  const float* dwn_bias = (const float*)d_in[7];
  float* out = (float*)d_out;

  // ws layout (bf16 elems): xb [T,H] | act [T, E*I] | W1d [E,R1,H] | W2t [H, E*I]
  const size_t nXb  = (size_t)Ttok * Hdim;
  const size_t nAct = (size_t)Ttok * K2;
  const size_t nW1  = (size_t)E8 * R1 * Hdim;

  uint16_t* xb  = (uint16_t*)d_ws;
  uint16_t* act = xb + nXb;
  uint16_t* w1d = act + nAct;
  uint16_t* w2t = w1d + nW1;

  static int attr_set = 0;
  if (!attr_set) {
    (void)hipFuncSetAttribute((const void*)gemm1_dp_kernel,
                              hipFuncAttributeMaxDynamicSharedMemorySize, 73728);
    (void)hipFuncSetAttribute((const void*)gemm2_dp_kernel,
                              hipFuncAttributeMaxDynamicSharedMemorySize, 73728);
    attr_set = 1;
  }

  cvt_x_kernel<<<dim3((Ttok * Hdim / 4 + 255) / 256), 256, 0, stream>>>(x, xb, Ttok * Hdim);
  dq_w_kernel<<<dim3((int)((size_t)E8 * R1 * Gg * 4 / 256)), 256, 0, stream>>>(gub_b, gub_s, w1d);
  dq_w2t_kernel<<<dim3((int)((size_t)E8 * Hdim * Gg * 4 / 256)), 256, 0, stream>>>(dwn_b, dwn_s, w2t);
  bias_init_kernel<<<dim3(3, Ttok), 256, 0, stream>>>(rw, dwn_bias, out);
  gemm1_dp_kernel<<<dim3(4, 45, 8), 256, 73728, stream>>>(xb, w1d, gub_bias, rw, act);
  gemm2_dp_kernel<<<dim3(4, 23, 12), 256, 73728, stream>>>(act, w2t, out);
}

// Round 7
// 995.770 us; speedup vs baseline: 1.0259x; 1.0259x over previous
//
#include <hip/hip_runtime.h>
#include <cstdint>

// ---------------------------------------------------------------------------
// MXFP4 GPT-OSS MoE experts: dense all-expert GLU MLP.
// Round 11: (a) gemms reverted to round-9 best (512 thr, 64x64 wave tile,
// 3-slot ring, vmcnt(3), gemm2 K-split 8). (b) cvt/dq_w/dq_w2t/bias fused
// into ONE prep_kernel (block-range dispatch) with 4-way ILP in dq paths
// (4 granules/thread at grid-quarter stride, coalesced) -- prep chain was
// ~2 TB/s vs 6.3 ceiling; theory: thin per-thread ILP + launch serialization.
// ---------------------------------------------------------------------------

typedef float  floatx4 __attribute__((ext_vector_type(4)));
typedef __bf16 bf16x8  __attribute__((ext_vector_type(8)));

#define E8   8
#define Hdim 2880
#define Idim 2880
#define Ttok 1024
#define R1   5760   // 2*I rows of gate_up weights
#define Gg   90     // scale groups per row (K/32)
#define K2   (E8 * Idim)   // 23040 flattened (e,i) K for GEMM2

// prep_kernel block ranges
#define NB_DQW  16200   // dq_w:  4,147,200 threads x 4 granules
#define NB_DQT  8100    // dq_w2t: 2,073,600 threads x 4 granules
#define NB_CVT  2880    // cvt_x: 737,280 threads x 4 floats
#define NB_BIAS 3072    // bias_init: 1024 x 3 blocks
#define DQW_T   4147200u  // granule stride (= #granules/4) for dq_w
#define DQT_T   2073600u  // granule stride for dq_w2t

__device__ __forceinline__ void load_lds16(const void* gptr, void* lptr) {
  __builtin_amdgcn_global_load_lds(
      (const __attribute__((address_space(1))) uint32_t*)gptr,
      (__attribute__((address_space(3))) uint32_t*)lptr, 16, 0, 0);
}

__device__ __forceinline__ uint32_t f2bf(float f) {  // RTN-even fp32->bf16
  uint32_t u = __float_as_uint(f);
  return (u + 0x7FFFu + ((u >> 16) & 1u)) >> 16;
}

__device__ __forceinline__ uint32_t perm(uint32_t hi, uint32_t lo, uint32_t sel) {
  return __builtin_amdgcn_perm(hi, lo, sel);
}

// Per-scale-group LUT: bf16 bit patterns of FP4 magnitudes 0..7 scaled by
// 2^(s-127), split into low/high bytes for v_perm lookup. Entry 0 stays 0.
struct DqLut { uint32_t Ll, Lh, Hl, Hh; };

__device__ __forceinline__ DqLut make_lut(int s) {
  uint32_t A  = ((uint32_t)(s - 127) << 7) & 0xFFFFu;
  uint32_t e1 = (0x3F00u + A) & 0xFFFFu, e2 = (0x3F80u + A) & 0xFFFFu;
  uint32_t e3 = (0x3FC0u + A) & 0xFFFFu, e4 = (0x4000u + A) & 0xFFFFu;
  uint32_t e5 = (0x4040u + A) & 0xFFFFu, e6 = (0x4080u + A) & 0xFFFFu;
  uint32_t e7 = (0x40C0u + A) & 0xFFFFu;
  uint32_t B01 = e1 << 16, B23 = e2 | (e3 << 16);
  uint32_t B45 = e4 | (e5 << 16), B67 = e6 | (e7 << 16);
  DqLut L;
  L.Ll = perm(B23, B01, 0x06040200u);
  L.Hl = perm(B23, B01, 0x07050301u);
  L.Lh = perm(B67, B45, 0x06040200u);
  L.Hh = perm(B67, B45, 0x07050301u);
  return L;
}

// 4 source dwords (1 packed byte each) -> 8 bf16 (4 dwords), interleaved order.
__device__ __forceinline__ uint4 dq8(const DqLut& L, int4 wr) {
  uint32_t p = perm((uint32_t)wr.y, (uint32_t)wr.x, 0x04000400u);
  uint32_t q = perm((uint32_t)wr.w, (uint32_t)wr.z, 0x04000400u);
  uint32_t w = perm(q, p, 0x05040100u);
  uint32_t ilo = w & 0x07070707u;
  uint32_t ihi = (w >> 4) & 0x07070707u;
  uint32_t Llo = perm(L.Lh, L.Ll, ilo);
  uint32_t Hlo = perm(L.Hh, L.Hl, ilo) | ((w << 4) & 0x80808080u);
  uint32_t Lhi = perm(L.Lh, L.Ll, ihi);
  uint32_t Hhi = perm(L.Hh, L.Hl, ihi) | (w & 0x80808080u);
  uint32_t t0 = perm(Hlo, Llo, 0x05010400u);
  uint32_t t1 = perm(Hlo, Llo, 0x07030602u);
  uint32_t t2 = perm(Hhi, Lhi, 0x05010400u);
  uint32_t t3 = perm(Hhi, Lhi, 0x07030602u);
  uint4 o;
  o.x = perm(t2, t0, 0x05040100u);
  o.y = perm(t2, t0, 0x07060302u);
  o.z = perm(t3, t1, 0x05040100u);
  o.w = perm(t3, t1, 0x07060302u);
  return o;
}

// ---------------------------------------------------------------------------
// Fused prep: [dq_w | dq_w2t | cvt_x | bias_init] by blockIdx range.
// dq paths: 4 independent granules per thread (grid-quarter stride keeps the
// wave's 16B/lane accesses contiguous); loads batched ahead of compute.
__global__ __launch_bounds__(256) void prep_kernel(
    const float* __restrict__ x, const float* __restrict__ rw,
    const int* __restrict__ gub_b, const int* __restrict__ gub_s,
    const int* __restrict__ dwn_b, const int* __restrict__ dwn_s,
    const float* __restrict__ dwn_bias,
    uint16_t* __restrict__ xb, uint16_t* __restrict__ w1d,
    uint16_t* __restrict__ w2t, float* __restrict__ out) {
  const int b = blockIdx.x;
  const int tid = threadIdx.x;

  if (b < NB_DQW) {
    // W1 dequant, layout preserved: granule G -> ((uint4*)w1d)[G]
    uint32_t j = (uint32_t)b * 256u + (uint32_t)tid;
    int4 w[4]; int sc[4];
    #pragma unroll
    for (int k = 0; k < 4; ++k) {
      size_t G = (size_t)j + (size_t)k * DQW_T;
      w[k]  = ((const int4*)gub_b)[G];
      sc[k] = gub_s[G >> 2];
    }
    #pragma unroll
    for (int k = 0; k < 4; ++k) {
      size_t G = (size_t)j + (size_t)k * DQW_T;
      ((uint4*)w1d)[G] = dq8(make_lut(sc[k]), w[k]);
    }
    return;
  }
  if (b < NB_DQW + NB_DQT) {
    // W2 dequant TRANSPOSED: [e][h][ig] granule -> w2t[(h*E8+e)*Idim + ig*32 + part*8]
    uint32_t j = (uint32_t)(b - NB_DQW) * 256u + (uint32_t)tid;
    int4 w[4]; int sc[4]; size_t og[4];
    #pragma unroll
    for (int k = 0; k < 4; ++k) {
      size_t G = (size_t)j + (size_t)k * DQT_T;
      w[k] = ((const int4*)dwn_b)[G];
      size_t g = G >> 2; int part = (int)(G & 3);
      sc[k] = dwn_s[g];
      int e  = (int)(g / ((size_t)Hdim * Gg));
      int rm = (int)(g % ((size_t)Hdim * Gg));
      int h  = rm / Gg;
      int ig = rm % Gg;
      og[k] = ((size_t)h * E8 + e) * Idim + (size_t)ig * 32 + part * 8;
    }
    #pragma unroll
    for (int k = 0; k < 4; ++k)
      *(uint4*)(w2t + og[k]) = dq8(make_lut(sc[k]), w[k]);
    return;
  }
  if (b < NB_DQW + NB_DQT + NB_CVT) {
    int i = ((b - NB_DQW - NB_DQT) * 256 + tid) * 4;
    float4 v = *(const float4*)(x + i);
    ushort4 o = make_ushort4((uint16_t)f2bf(v.x), (uint16_t)f2bf(v.y),
                             (uint16_t)f2bf(v.z), (uint16_t)f2bf(v.w));
    *(ushort4*)(xb + i) = o;
    return;
  }
  {
    int idx = b - NB_DQW - NB_DQT - NB_CVT;
    int t = idx / 3, sub = idx % 3;
    int h4 = (sub * 256 + tid) * 4;
    if (h4 >= Hdim) return;
    float4 s = make_float4(0.f, 0.f, 0.f, 0.f);
    #pragma unroll
    for (int e = 0; e < E8; ++e) {
      float w = rw[t * E8 + e];
      float4 bb = *(const float4*)(dwn_bias + (size_t)e * Hdim + h4);
      s.x += w * bb.x; s.y += w * bb.y; s.z += w * bb.z; s.w += w * bb.w;
    }
    *(float4*)(out + (size_t)t * Hdim + h4) = s;
  }
}

// ---------------------------------------------------------------------------
// GEMM1 deep-pipelined: BM=256 tokens x BN=128 f-rows x BK=32, 512 threads
// (8 waves, 4M x 2N, wave tile 64x64). LDS: 3-slot ring (A 16KB + B 8KB per
// slot = 72KB). Distance-2 prefetch; per K-step: vmcnt(3) -> s_barrier ->
// issue 3 global_load_lds for tile j+2 -> 8 ds_read_b128 -> 16 MFMA.
// Swizzle: granule p in LDS holds global granule p ^ ((row>>1)&3) (rows 64B).
// Epilogue: GLU + bias, pre-multiply by rw[t,e], store bf16 to act[t][(e,i)].
__global__ __launch_bounds__(512) void gemm1_dp_kernel(
    const uint16_t* __restrict__ xb, const uint16_t* __restrict__ w1d,
    const float* __restrict__ bias, const float* __restrict__ rw,
    uint16_t* __restrict__ act) {
  extern __shared__ uint16_t smem[];          // 3*8192 (A) + 3*4096 (B)
  uint16_t* sAr = smem;                       // [3][256*32]
  uint16_t* sBr = smem + 3 * 8192;            // [3][128*32]
  const int tid  = threadIdx.x;
  const int lane = tid & 63, wv = tid >> 6;
  const int wm = wv >> 1, wn = wv & 1;        // 4 M-waves x 2 N-waves
  const int col = lane & 15, quad = lane >> 4;
  const int e  = blockIdx.z;
  const int t0 = blockIdx.x * 256;
  const int i0 = blockIdx.y * 64;

  floatx4 acc[4][4] = {};

  const uint16_t* aSrc0;
  const uint16_t* aSrc1;
  const uint16_t* bSrc;
  {
    int L0 = tid;            // issue 0: rows 0..127
    int r0 = L0 >> 2;
    int g0 = (L0 & 3) ^ ((r0 >> 1) & 3);
    aSrc0 = xb + (size_t)(t0 + r0) * Hdim + g0 * 8;
    int L1 = 512 + tid;      // issue 1: rows 128..255
    int r1 = L1 >> 2;
    int g1 = (L1 & 3) ^ ((r1 >> 1) & 3);
    aSrc1 = xb + (size_t)(t0 + r1) * Hdim + g1 * 8;
    int rb = tid >> 2;       // B rows 0..127 (deinterleaved gate/up blocks)
    int gb = (tid & 3) ^ ((rb >> 1) & 3);
    int orig = 2 * (((rb >> 6) << 5) + (rb & 31)) + ((rb >> 5) & 1);
    bSrc = w1d + ((size_t)e * R1 + 2 * i0 + orig) * Hdim + gb * 8;
  }
  const int aOff0 = (wv * 64) * 8;
  const int aOff1 = (512 + wv * 64) * 8;
  const int bOff  = (wv * 64) * 8;

  auto STAGE = [&](int kt, int slot) {
    const int k0 = kt * 32;
    uint16_t* A = sAr + slot * 8192;
    uint16_t* B = sBr + slot * 4096;
    load_lds16(aSrc0 + k0, A + aOff0);
    load_lds16(aSrc1 + k0, A + aOff1);
    load_lds16(bSrc + k0, B + bOff);
  };

  STAGE(0, 0);
  STAGE(1, 1);

  int sr = 0;  // read slot = j % 3
  for (int j = 0; j < 90; ++j) {
    asm volatile("s_waitcnt vmcnt(3)" ::: "memory");
    __builtin_amdgcn_s_barrier();
    asm volatile("" ::: "memory");
    int js = j + 2; if (js > 89) js = 89;
    int sw = sr + 2; if (sw >= 3) sw -= 3;
    STAGE(js, sw);

    const uint16_t* A = sAr + sr * 8192;
    const uint16_t* B = sBr + sr * 4096;
    bf16x8 af[4], bfr[4];
    #pragma unroll
    for (int fm = 0; fm < 4; ++fm) {
      int row = wm * 64 + fm * 16 + col;
      int g = quad ^ ((row >> 1) & 3);
      af[fm] = *(const bf16x8*)&A[row * 32 + g * 8];
    }
    #pragma unroll
    for (int fn = 0; fn < 4; ++fn) {
      int row = wn * 64 + fn * 16 + col;
      int g = quad ^ ((row >> 1) & 3);
      bfr[fn] = *(const bf16x8*)&B[row * 32 + g * 8];
    }
    __builtin_amdgcn_s_setprio(1);
    #pragma unroll
    for (int fm = 0; fm < 4; ++fm)
      #pragma unroll
      for (int fn = 0; fn < 4; ++fn)
        acc[fm][fn] = __builtin_amdgcn_mfma_f32_16x16x32_bf16(
            af[fm], bfr[fn], acc[fm][fn], 0, 0, 0);
    __builtin_amdgcn_s_setprio(0);
    sr = (sr + 1 == 3) ? 0 : sr + 1;
  }

  #pragma unroll
  for (int fm = 0; fm < 4; ++fm) {
    #pragma unroll
    for (int p = 0; p < 2; ++p) {
      floatx4 ga = acc[fm][p], ua = acc[fm][p + 2];
      int ig = i0 + wn * 32 + p * 16 + col;
      float bg = bias[(size_t)e * R1 + 2 * ig];
      float bu = bias[(size_t)e * R1 + 2 * ig + 1];
      #pragma unroll
      for (int r = 0; r < 4; ++r) {
        int t = t0 + wm * 64 + fm * 16 + quad * 4 + r;
        float gate = fminf(ga[r] + bg, 7.0f);
        float up   = fminf(fmaxf(ua[r] + bu, -7.0f), 7.0f);
        float glu  = gate / (1.0f + __expf(-1.702f * gate));
        float a    = rw[t * E8 + e] * (up + 1.0f) * glu;
        act[((size_t)t * E8 + e) * Idim + ig] = (uint16_t)f2bf(a);
      }
    }
  }
}

// ---------------------------------------------------------------------------
// GEMM2 deep-pipelined, gemm1 geometry: M=1024 x N=2880(pad->2944) x K=23040.
// BM=256, BN=128, BK=32, K-split 8 -> grid (4,23,8)=736 blocks (2.87/CU).
// 512 thr (8 waves, 4M x 2N, wave 64x64). 3-slot 72KB ring, distance-2
// prefetch, vmcnt(3) + single s_barrier per K-step, setprio-wrapped MFMA.
// B staging rows clamped to h<=2879 (pad); epilogue atomicAdd guarded h<2880.
__global__ __launch_bounds__(512) void gemm2_dp_kernel(
    const uint16_t* __restrict__ actT, const uint16_t* __restrict__ w2t,
    float* __restrict__ out) {
  extern __shared__ uint16_t smem[];          // 3*8192 (A) + 3*4096 (B)
  uint16_t* sAr = smem;                       // [3][256*32]
  uint16_t* sBr = smem + 3 * 8192;            // [3][128*32]
  const int tid  = threadIdx.x;
  const int lane = tid & 63, wv = tid >> 6;
  const int wm = wv >> 1, wn = wv & 1;        // 4 M-waves x 2 N-waves
  const int col = lane & 15, quad = lane >> 4;
  const int t0 = blockIdx.x * 256;
  const int h0 = blockIdx.y * 128;            // last block: 2816..2943 (pad)
  const int kbase = blockIdx.z * (K2 / 8);    // 2880 per split

  floatx4 acc[4][4] = {};

  const uint16_t* aSrc0;
  const uint16_t* aSrc1;
  const uint16_t* bSrc;
  {
    int L0 = tid;            // A rows 0..127
    int r0 = L0 >> 2;
    int g0 = (L0 & 3) ^ ((r0 >> 1) & 3);
    aSrc0 = actT + (size_t)(t0 + r0) * K2 + kbase + g0 * 8;
    int L1 = 512 + tid;      // A rows 128..255
    int r1 = L1 >> 2;
    int g1 = (L1 & 3) ^ ((r1 >> 1) & 3);
    aSrc1 = actT + (size_t)(t0 + r1) * K2 + kbase + g1 * 8;
    int rb = tid >> 2;       // B rows 0..127 of w2t panel
    int gb = (tid & 3) ^ ((rb >> 1) & 3);
    int hb = h0 + rb; if (hb > Hdim - 1) hb = Hdim - 1;   // pad-tile clamp
    bSrc = w2t + (size_t)hb * K2 + kbase + gb * 8;
  }
  const int aOff0 = (wv * 64) * 8;
  const int aOff1 = (512 + wv * 64) * 8;
  const int bOff  = (wv * 64) * 8;

  auto STAGE = [&](int kt, int slot) {
    const int k0 = kt * 32;
    uint16_t* A = sAr + slot * 8192;
    uint16_t* B = sBr + slot * 4096;
    load_lds16(aSrc0 + k0, A + aOff0);
    load_lds16(aSrc1 + k0, A + aOff1);
    load_lds16(bSrc + k0, B + bOff);
  };

  STAGE(0, 0);
  STAGE(1, 1);

  int sr = 0;  // read slot = j % 3
  for (int j = 0; j < 90; ++j) {
    asm volatile("s_waitcnt vmcnt(3)" ::: "memory");
    __builtin_amdgcn_s_barrier();
    asm volatile("" ::: "memory");
    int js = j + 2; if (js > 89) js = 89;
    int sw = sr + 2; if (sw >= 3) sw -= 3;
    STAGE(js, sw);

    const uint16_t* A = sAr + sr * 8192;
    const uint16_t* B = sBr + sr * 4096;
    bf16x8 af[4], bfr[4];
    #pragma unroll
    for (int fm = 0; fm < 4; ++fm) {
      int row = wm * 64 + fm * 16 + col;
      int g = quad ^ ((row >> 1) & 3);
      af[fm] = *(const bf16x8*)&A[row * 32 + g * 8];
    }
    #pragma unroll
    for (int fn = 0; fn < 4; ++fn) {
      int row = wn * 64 + fn * 16 + col;
      int g = quad ^ ((row >> 1) & 3);
      bfr[fn] = *(const bf16x8*)&B[row * 32 + g * 8];
    }
    __builtin_amdgcn_s_setprio(1);
    #pragma unroll
    for (int fm = 0; fm < 4; ++fm)
      #pragma unroll
      for (int fn = 0; fn < 4; ++fn)
        acc[fm][fn] = __builtin_amdgcn_mfma_f32_16x16x32_bf16(
            af[fm], bfr[fn], acc[fm][fn], 0, 0, 0);
    __builtin_amdgcn_s_setprio(0);
    sr = (sr + 1 == 3) ? 0 : sr + 1;
  }

  #pragma unroll
  for (int fm = 0; fm < 4; ++fm)
    #pragma unroll
    for (int fn = 0; fn < 4; ++fn) {
      int h = h0 + wn * 64 + fn * 16 + col;
      if (h < Hdim) {
        #pragma unroll
        for (int r = 0; r < 4; ++r) {
          int t = t0 + wm * 64 + fm * 16 + quad * 4 + r;
          atomicAdd(out + (size_t)t * Hdim + h, acc[fm][fn][r]);
        }
      }
    }
}

// ---------------------------------------------------------------------------
extern "C" void kernel_launch(void* const* d_in, const int* in_sizes, int n_in,
                              void* d_out, int out_size, void* d_ws, size_t ws_size,
                              hipStream_t stream) {
  (void)in_sizes; (void)n_in; (void)out_size; (void)ws_size;
  const float* x        = (const float*)d_in[0];
  const float* rw       = (const float*)d_in[1];
  const int*   gub_b    = (const int*)d_in[2];
  const int*   gub_s    = (const int*)d_in[3];
  const float* gub_bias = (const float*)d_in[4];
  const int*   dwn_b    = (const int*)d_in[5];
  const int*   dwn_s    = (const int*)d_in[6];
  const float* dwn_bias = (const float*)d_in[7];
  float* out = (float*)d_out;

  // ws layout (bf16 elems): xb [T,H] | act [T, E*I] | W1d [E,R1,H] | W2t [H, E*I]
  const size_t nXb  = (size_t)Ttok * Hdim;
  const size_t nAct = (size_t)Ttok * K2;
  const size_t nW1  = (size_t)E8 * R1 * Hdim;

  uint16_t* xb  = (uint16_t*)d_ws;
  uint16_t* act = xb + nXb;
  uint16_t* w1d = act + nAct;
  uint16_t* w2t = w1d + nW1;

  static int attr_set = 0;
  if (!attr_set) {
    (void)hipFuncSetAttribute((const void*)gemm1_dp_kernel,
                              hipFuncAttributeMaxDynamicSharedMemorySize, 73728);
    (void)hipFuncSetAttribute((const void*)gemm2_dp_kernel,
                              hipFuncAttributeMaxDynamicSharedMemorySize, 73728);
    attr_set = 1;
  }

  prep_kernel<<<dim3(NB_DQW + NB_DQT + NB_CVT + NB_BIAS), 256, 0, stream>>>(
      x, rw, gub_b, gub_s, dwn_b, dwn_s, dwn_bias, xb, w1d, w2t, out);
  gemm1_dp_kernel<<<dim3(4, 45, 8), 512, 73728, stream>>>(xb, w1d, gub_bias, rw, act);
  gemm2_dp_kernel<<<dim3(4, 23, 8), 512, 73728, stream>>>(act, w2t, out);
}